// Round 1
// baseline (911.339 us; speedup 1.0000x reference)
//
#include <hip/hip_runtime.h>
#include <hip/hip_bf16.h>

typedef __attribute__((ext_vector_type(8))) short bf16x8;
typedef __attribute__((ext_vector_type(4))) float f32x4;

#define B_   4
#define T_   2048
#define DIM_ 1024
#define H_   64
#define NS_  32
#define K_   8
#define HV_  32
#define NTOK  (B_ * T_)   /* 8192 */
#define QKV_N 6144        /* q(2048) | k(2048) | v(2048) */
#define RA_N  128         /* router logits(64) | a(64) */

// ---------------------------------------------------------------- helpers
__device__ __forceinline__ void gld_lds16(const void* g, void* s) {
  __builtin_amdgcn_global_load_lds(
      (const __attribute__((address_space(1))) void*)g,
      (__attribute__((address_space(3))) void*)s, 16, 0, 0);
}

// ---------------------------------------------------------------- prep
__global__ __launch_bounds__(256) void cast_bf16(const float* __restrict__ in,
                                                 __hip_bfloat16* __restrict__ out, int n4) {
  int i = blockIdx.x * 256 + threadIdx.x;
  if (i >= n4) return;
  const float4 v = *(const float4*)(in + (size_t)i * 4);
  union { short4 s4; __hip_bfloat16 h[4]; } u;
  u.h[0] = __float2bfloat16(v.x); u.h[1] = __float2bfloat16(v.y);
  u.h[2] = __float2bfloat16(v.z); u.h[3] = __float2bfloat16(v.w);
  *(short4*)(out + (size_t)i * 4) = u.s4;
}

// B2[d][s*32+v] = Wo[d][v]  (slot-replicated Wo, bf16), 1024x256
__global__ __launch_bounds__(256) void build_b2(const float* __restrict__ Wo,
                                                __hip_bfloat16* __restrict__ B2) {
  int i = blockIdx.x * 256 + threadIdx.x;           // 262144
  int d = i >> 8, c = i & 255;
  B2[i] = __float2bfloat16(Wo[d * 32 + (c & 31)]);
}

// WT[d][h] = (h<64 ? Wr : Wa)[h][d]   fp32, 1024x128
__global__ __launch_bounds__(256) void build_wt(const float* __restrict__ Wr,
                                                const float* __restrict__ Wa,
                                                float* __restrict__ WT) {
  int i = blockIdx.x * 256 + threadIdx.x;           // 131072
  int d = i >> 7, h = i & 127;
  WT[i] = (h < 64) ? Wr[h * 1024 + d] : Wa[(h - 64) * 1024 + d];
}

// ---------------------------------------------------------------- router GEMM (fp32 exact)
// RA[m][0..64) = logits, RA[m][64..128) = a.  One wave: 8 tokens x 128 heads.
__global__ __launch_bounds__(256) void router_gemm(const float* __restrict__ x,
                                                   const float* __restrict__ WT,
                                                   float* __restrict__ RA) {
  const int w = threadIdx.x >> 6, l = threadIdx.x & 63;
  const int t0 = blockIdx.x * 32 + w * 8;
  float a0[8] = {}, a1[8] = {};
  for (int d = 0; d < DIM_; d += 4) {
    float4 xv[8];
#pragma unroll
    for (int i = 0; i < 8; ++i) xv[i] = *(const float4*)(x + (size_t)(t0 + i) * DIM_ + d);
#pragma unroll
    for (int j = 0; j < 4; ++j) {
      const float w0 = WT[(d + j) * RA_N + l];
      const float w1 = WT[(d + j) * RA_N + 64 + l];
#pragma unroll
      for (int i = 0; i < 8; ++i) {
        const float xs = ((const float*)&xv[i])[j];
        a0[i] = fmaf(xs, w0, a0[i]);
        a1[i] = fmaf(xs, w1, a1[i]);
      }
    }
  }
#pragma unroll
  for (int i = 0; i < 8; ++i) {
    RA[(size_t)(t0 + i) * RA_N + l] = a0[i];
    RA[(size_t)(t0 + i) * RA_N + 64 + l] = a1[i];
  }
}

// ---------------------------------------------------------------- top-k + decay (1 wave / token)
__global__ __launch_bounds__(256) void router_topk(const float* __restrict__ RA,
                                                   const float* __restrict__ A_log,
                                                   const float* __restrict__ dt_bias,
                                                   int* __restrict__ idxb,
                                                   float* __restrict__ rwb,
                                                   float* __restrict__ decb) {
  const int w = threadIdx.x >> 6, l = threadIdx.x & 63;
  const int m = blockIdx.x * 4 + w;
  float zcur = RA[(size_t)m * RA_N + l];
  const int idx = l;
  float z0 = 0.f, myz = 0.f;
  int myh = 0;
#pragma unroll
  for (int i = 0; i < 8; ++i) {
    float v = zcur; int vi = idx;
#pragma unroll
    for (int off = 1; off < 64; off <<= 1) {
      float ov = __shfl_xor(v, off);
      int   oi = __shfl_xor(vi, off);
      if (ov > v || (ov == v && oi < vi)) { v = ov; vi = oi; }
    }
    if (i == 0) z0 = v;
    if (l == i) { myz = v; myh = vi; }       // lane i owns slot i (preserves jax top_k order)
    if (idx == vi) zcur = -__builtin_inff(); // mask winner
  }
  float e = (l < 8) ? expf(myz - z0) : 0.f;
  float es = e;
  es += __shfl_xor(es, 1); es += __shfl_xor(es, 2); es += __shfl_xor(es, 4);
  if (l < 8) {
    const float a  = RA[(size_t)m * RA_N + 64 + myh];
    const float xb = a + dt_bias[myh];
    const float dt = (xb > 20.f) ? xb : log1pf(expf(xb));
    idxb[m * 8 + l] = myh;
    rwb [m * 8 + l] = e / es;
    decb[m * 8 + l] = expf(-expf(A_log[myh]) * dt);
  }
}

// ---------------------------------------------------------------- bf16 MFMA GEMM, C = A * B^T
// A[M,K] bf16 packed, B[N,K] bf16 packed. 128x128 tile, BK=32, 4 waves, glds16.
template <bool OUT_BF16>
__global__ __launch_bounds__(256) void gemm_bt(const short* __restrict__ A,
                                               const short* __restrict__ Bm,
                                               void* __restrict__ Cout,
                                               int M, int N, int K) {
  __shared__ __align__(16) short As[128 * 32];
  __shared__ __align__(16) short Bs[128 * 32];
  const int tid = threadIdx.x;
  const int w = tid >> 6, l = tid & 63;
  const int m0 = blockIdx.y * 128, n0 = blockIdx.x * 128;
  const int wr = (w >> 1) * 64, wc = (w & 1) * 64;
  const int rsub = l >> 2, csub = (l & 3) * 8;   // staging: row within 16, 16B chunk
  const int lr = l & 15, lk = l >> 4;            // fragment lane decode
  f32x4 acc[4][4] = {};

  for (int k0 = 0; k0 < K; k0 += 32) {
#pragma unroll
    for (int j = 0; j < 2; ++j) {
      const int ra = w * 32 + j * 16;
      gld_lds16(A  + (size_t)(m0 + ra + rsub) * K + k0 + csub, As + ra * 32);
      gld_lds16(Bm + (size_t)(n0 + ra + rsub) * K + k0 + csub, Bs + ra * 32);
    }
    __syncthreads();
    bf16x8 af[4], bfr[4];
#pragma unroll
    for (int i = 0; i < 4; ++i) af[i]  = *(const bf16x8*)(As + (wr + i * 16 + lr) * 32 + lk * 8);
#pragma unroll
    for (int j = 0; j < 4; ++j) bfr[j] = *(const bf16x8*)(Bs + (wc + j * 16 + lr) * 32 + lk * 8);
#pragma unroll
    for (int i = 0; i < 4; ++i)
#pragma unroll
      for (int j = 0; j < 4; ++j)
        acc[i][j] = __builtin_amdgcn_mfma_f32_16x16x32_bf16(af[i], bfr[j], acc[i][j], 0, 0, 0);
    __syncthreads();
  }
  // C/D: col = lane&15, row = (lane>>4)*4 + reg
#pragma unroll
  for (int i = 0; i < 4; ++i)
#pragma unroll
    for (int j = 0; j < 4; ++j) {
      const size_t row0 = (size_t)m0 + wr + i * 16 + lk * 4;
      const size_t col  = (size_t)n0 + wc + j * 16 + lr;
#pragma unroll
      for (int r = 0; r < 4; ++r) {
        if constexpr (OUT_BF16)
          ((__hip_bfloat16*)Cout)[(row0 + r) * N + col] = __float2bfloat16(acc[i][j][r]);
        else
          ((float*)Cout)[(row0 + r) * N + col] = acc[i][j][r];
      }
    }
}

// ---------------------------------------------------------------- gather selected heads -> records
// rec[(b*K+s)*T + t][128]: k[0..32) q[32..64) v[64..96) d[96] wt[97]
__global__ __launch_bounds__(256) void gather_records(const __hip_bfloat16* __restrict__ qkv,
                                                      const int* __restrict__ idxb,
                                                      const float* __restrict__ rwb,
                                                      const float* __restrict__ decb,
                                                      float* __restrict__ rec) {
  const int w = threadIdx.x >> 6, l = threadIdx.x & 63;
  const long rid = (long)blockIdx.x * 4 + w;    // < B*K*T = 65536
  const int t  = (int)(rid & (T_ - 1));
  const int bs = (int)(rid >> 11);
  const int b = bs >> 3, s = bs & 7;
  const long m = (long)b * T_ + t;
  const int h = idxb[m * 8 + s];
  float* r = rec + rid * 128;
  const int half = l >> 5, li = l & 31;         // half0 = q, half1 = k

  const long base = m * QKV_N + (long)h * 32 + li + (half ? 2048 : 0);
  const float xr = __bfloat162float(qkv[base]);
  const float sx = xr / (1.f + expf(-xr));      // silu
  float ss = sx * sx;
  ss += __shfl_xor(ss, 1);  ss += __shfl_xor(ss, 2);  ss += __shfl_xor(ss, 4);
  ss += __shfl_xor(ss, 8);  ss += __shfl_xor(ss, 16);
  const float outv = sx * rsqrtf(ss + 1e-6f);
  r[half ? li : (32 + li)] = outv;

  if (half == 0) {
    const float xv = __bfloat162float(qkv[m * QKV_N + 4096 + (long)h * 32 + li]);
    r[64 + li] = xv / (1.f + expf(-xv));        // silu(v), no l2norm
  }
  if (l == 0) { r[96] = decb[m * 8 + s]; r[97] = rwb[m * 8 + s]; }
}

// ---------------------------------------------------------------- recurrent scan
// 1 block / (b,slot); wave w owns v in [w*8, w*8+8); lane: v = w*8+(l&7), n0 = (l>>3)*4
__global__ __launch_bounds__(256) void scan_kernel(const float* __restrict__ rec,
                                                   const float* __restrict__ S0,
                                                   __hip_bfloat16* __restrict__ Y,
                                                   float* __restrict__ Sfin) {
  const int w = threadIdx.x >> 6, l = threadIdx.x & 63;
  const int bs = blockIdx.x;
  const int b = bs >> 3, s = bs & 7;
  const int v = w * 8 + (l & 7);
  const int n0 = (l >> 3) * 4;
  const float* r0 = rec + (size_t)bs * T_ * 128;
  const size_t sb = ((size_t)bs * NS_ + n0) * HV_ + v;
  float s0 = S0[sb], s1 = S0[sb + HV_], s2 = S0[sb + 2 * HV_], s3 = S0[sb + 3 * HV_];
  __hip_bfloat16* Yrow = Y + (size_t)b * T_ * 256 + s * 32 + v;

  float4 kA, qA; float vA, dA, wA;
  float4 kB, qB; float vB, dB, wB;
  kA = *(const float4*)(r0 + n0); qA = *(const float4*)(r0 + 32 + n0);
  vA = r0[64 + v]; dA = r0[96]; wA = r0[97];

  for (int t = 0; t < T_; t += 2) {
    const float* rp1 = r0 + (size_t)(t + 1) * 128;
    kB = *(const float4*)(rp1 + n0); qB = *(const float4*)(rp1 + 32 + n0);
    vB = rp1[64 + v]; dB = rp1[96]; wB = rp1[97];

    s0 = fmaf(dA, s0, kA.x * vA);
    s1 = fmaf(dA, s1, kA.y * vA);
    s2 = fmaf(dA, s2, kA.z * vA);
    s3 = fmaf(dA, s3, kA.w * vA);
    float p = fmaf(qA.x, s0, fmaf(qA.y, s1, fmaf(qA.z, s2, qA.w * s3)));
    p += __shfl_xor(p, 8); p += __shfl_xor(p, 16); p += __shfl_xor(p, 32);
    if (l < 8) Yrow[(size_t)t * 256] = __float2bfloat16(wA * p);

    if (t + 2 < T_) {
      const float* rp2 = r0 + (size_t)(t + 2) * 128;
      kA = *(const float4*)(rp2 + n0); qA = *(const float4*)(rp2 + 32 + n0);
      vA = rp2[64 + v]; dA = rp2[96]; wA = rp2[97];
    }

    s0 = fmaf(dB, s0, kB.x * vB);
    s1 = fmaf(dB, s1, kB.y * vB);
    s2 = fmaf(dB, s2, kB.z * vB);
    s3 = fmaf(dB, s3, kB.w * vB);
    float p2 = fmaf(qB.x, s0, fmaf(qB.y, s1, fmaf(qB.z, s2, qB.w * s3)));
    p2 += __shfl_xor(p2, 8); p2 += __shfl_xor(p2, 16); p2 += __shfl_xor(p2, 32);
    if (l < 8) Yrow[(size_t)(t + 1) * 256] = __float2bfloat16(wB * p2);
  }
  Sfin[sb] = s0; Sfin[sb + HV_] = s1; Sfin[sb + 2 * HV_] = s2; Sfin[sb + 3 * HV_] = s3;
}

// ---------------------------------------------------------------- launch
extern "C" void kernel_launch(void* const* d_in, const int* in_sizes, int n_in,
                              void* d_out, int out_size, void* d_ws, size_t ws_size,
                              hipStream_t stream) {
  const float* x       = (const float*)d_in[0];
  const float* Wr      = (const float*)d_in[1];
  const float* Wq      = (const float*)d_in[2];
  const float* Wk      = (const float*)d_in[3];
  const float* Wv      = (const float*)d_in[4];
  const float* Wa      = (const float*)d_in[5];
  const float* A_log   = (const float*)d_in[6];
  const float* dt_bias = (const float*)d_in[7];
  const float* Wo      = (const float*)d_in[8];
  const float* S0      = (const float*)d_in[9];
  float* out = (float*)d_out;

  char* p = (char*)d_ws;
  auto alloc = [&](size_t bytes) -> void* {
    void* r = (void*)p; p += (bytes + 255) & ~(size_t)255; return r;
  };
  __hip_bfloat16* x_bf = (__hip_bfloat16*)alloc((size_t)NTOK * DIM_ * 2);
  __hip_bfloat16* Wqkv = (__hip_bfloat16*)alloc((size_t)QKV_N * DIM_ * 2);
  __hip_bfloat16* qkv  = (__hip_bfloat16*)alloc((size_t)NTOK * QKV_N * 2);
  float* WT   = (float*)alloc((size_t)DIM_ * RA_N * 4);
  float* RA   = (float*)alloc((size_t)NTOK * RA_N * 4);
  int*   idxb = (int*)  alloc((size_t)NTOK * K_ * 4);
  float* rwb  = (float*)alloc((size_t)NTOK * K_ * 4);
  float* decb = (float*)alloc((size_t)NTOK * K_ * 4);
  float* recb = (float*)alloc((size_t)B_ * K_ * T_ * 128 * 4);
  __hip_bfloat16* Yb = (__hip_bfloat16*)alloc((size_t)NTOK * 256 * 2);
  __hip_bfloat16* B2 = (__hip_bfloat16*)alloc((size_t)DIM_ * 256 * 2);

  cast_bf16<<<NTOK * DIM_ / 4 / 256, 256, 0, stream>>>(x, x_bf, NTOK * DIM_ / 4);
  cast_bf16<<<2048, 256, 0, stream>>>(Wq, Wqkv,               2048 * 1024 / 4);
  cast_bf16<<<2048, 256, 0, stream>>>(Wk, Wqkv + 2048 * 1024, 2048 * 1024 / 4);
  cast_bf16<<<2048, 256, 0, stream>>>(Wv, Wqkv + 4096 * 1024, 2048 * 1024 / 4);
  build_b2<<<DIM_ * 256 / 256, 256, 0, stream>>>(Wo, B2);
  build_wt<<<DIM_ * RA_N / 256, 256, 0, stream>>>(Wr, Wa, WT);

  router_gemm<<<NTOK / 32, 256, 0, stream>>>(x, WT, RA);
  router_topk<<<NTOK / 4, 256, 0, stream>>>(RA, A_log, dt_bias, idxb, rwb, decb);

  gemm_bt<true><<<dim3(QKV_N / 128, NTOK / 128), 256, 0, stream>>>(
      (const short*)x_bf, (const short*)Wqkv, qkv, NTOK, QKV_N, DIM_);

  gather_records<<<B_ * K_ * T_ / 4, 256, 0, stream>>>(qkv, idxb, rwb, decb, recb);
  scan_kernel<<<B_ * K_, 256, 0, stream>>>(recb, S0, Yb, out + (size_t)NTOK * DIM_);

  gemm_bt<false><<<dim3(DIM_ / 128, NTOK / 128), 256, 0, stream>>>(
      (const short*)Yb, (const short*)B2, out, NTOK, DIM_, 256);
}

// Round 2
// 366.916 us; speedup vs baseline: 2.4838x; 2.4838x over previous
//
#include <hip/hip_runtime.h>
#include <hip/hip_bf16.h>

typedef __attribute__((ext_vector_type(8))) short bf16x8;
typedef __attribute__((ext_vector_type(4))) float f32x4;

#define B_   4
#define T_   2048
#define DIM_ 1024
#define H_   64
#define NS_  32
#define K_   8
#define HV_  32
#define NTOK  (B_ * T_)   /* 8192 */
#define QKV_N 6144        /* q(2048) | k(2048) | v(2048) */
#define RA_N  128         /* router logits(64) | a(64) */
#define CL_   64          /* scan chunk length */
#define NC_   (T_ / CL_)  /* 32 chunks per slot */
#define NSLOT (B_ * K_)   /* 32 */

// ---------------------------------------------------------------- helpers
__device__ __forceinline__ void gld_lds16(const void* g, void* s) {
  __builtin_amdgcn_global_load_lds(
      (const __attribute__((address_space(1))) void*)g,
      (__attribute__((address_space(3))) void*)s, 16, 0, 0);
}

// ---------------------------------------------------------------- prep
__global__ __launch_bounds__(256) void cast_bf16(const float* __restrict__ in,
                                                 __hip_bfloat16* __restrict__ out, int n4) {
  int i = blockIdx.x * 256 + threadIdx.x;
  if (i >= n4) return;
  const float4 v = *(const float4*)(in + (size_t)i * 4);
  union { short4 s4; __hip_bfloat16 h[4]; } u;
  u.h[0] = __float2bfloat16(v.x); u.h[1] = __float2bfloat16(v.y);
  u.h[2] = __float2bfloat16(v.z); u.h[3] = __float2bfloat16(v.w);
  *(short4*)(out + (size_t)i * 4) = u.s4;
}

// B2[d][s*32+v] = Wo[d][v]  (slot-replicated Wo, bf16), 1024x256
__global__ __launch_bounds__(256) void build_b2(const float* __restrict__ Wo,
                                                __hip_bfloat16* __restrict__ B2) {
  int i = blockIdx.x * 256 + threadIdx.x;           // 262144
  int d = i >> 8, c = i & 255;
  B2[i] = __float2bfloat16(Wo[d * 32 + (c & 31)]);
}

// WT[d][h] = (h<64 ? Wr : Wa)[h][d]   fp32, 1024x128
__global__ __launch_bounds__(256) void build_wt(const float* __restrict__ Wr,
                                                const float* __restrict__ Wa,
                                                float* __restrict__ WT) {
  int i = blockIdx.x * 256 + threadIdx.x;           // 131072
  int d = i >> 7, h = i & 127;
  WT[i] = (h < 64) ? Wr[h * 1024 + d] : Wa[(h - 64) * 1024 + d];
}

// ---------------------------------------------------------------- router GEMM (fp32 exact)
__global__ __launch_bounds__(256) void router_gemm(const float* __restrict__ x,
                                                   const float* __restrict__ WT,
                                                   float* __restrict__ RA) {
  const int w = threadIdx.x >> 6, l = threadIdx.x & 63;
  const int t0 = blockIdx.x * 32 + w * 8;
  float a0[8] = {}, a1[8] = {};
  for (int d = 0; d < DIM_; d += 4) {
    float4 xv[8];
#pragma unroll
    for (int i = 0; i < 8; ++i) xv[i] = *(const float4*)(x + (size_t)(t0 + i) * DIM_ + d);
#pragma unroll
    for (int j = 0; j < 4; ++j) {
      const float w0 = WT[(d + j) * RA_N + l];
      const float w1 = WT[(d + j) * RA_N + 64 + l];
#pragma unroll
      for (int i = 0; i < 8; ++i) {
        const float xs = ((const float*)&xv[i])[j];
        a0[i] = fmaf(xs, w0, a0[i]);
        a1[i] = fmaf(xs, w1, a1[i]);
      }
    }
  }
#pragma unroll
  for (int i = 0; i < 8; ++i) {
    RA[(size_t)(t0 + i) * RA_N + l] = a0[i];
    RA[(size_t)(t0 + i) * RA_N + 64 + l] = a1[i];
  }
}

// ---------------------------------------------------------------- top-k + decay (1 wave / token)
__global__ __launch_bounds__(256) void router_topk(const float* __restrict__ RA,
                                                   const float* __restrict__ A_log,
                                                   const float* __restrict__ dt_bias,
                                                   int* __restrict__ idxb,
                                                   float* __restrict__ rwb,
                                                   float* __restrict__ decb) {
  const int w = threadIdx.x >> 6, l = threadIdx.x & 63;
  const int m = blockIdx.x * 4 + w;
  float zcur = RA[(size_t)m * RA_N + l];
  const int idx = l;
  float z0 = 0.f, myz = 0.f;
  int myh = 0;
#pragma unroll
  for (int i = 0; i < 8; ++i) {
    float v = zcur; int vi = idx;
#pragma unroll
    for (int off = 1; off < 64; off <<= 1) {
      float ov = __shfl_xor(v, off);
      int   oi = __shfl_xor(vi, off);
      if (ov > v || (ov == v && oi < vi)) { v = ov; vi = oi; }
    }
    if (i == 0) z0 = v;
    if (l == i) { myz = v; myh = vi; }
    if (idx == vi) zcur = -__builtin_inff();
  }
  float e = (l < 8) ? expf(myz - z0) : 0.f;
  float es = e;
  es += __shfl_xor(es, 1); es += __shfl_xor(es, 2); es += __shfl_xor(es, 4);
  if (l < 8) {
    const float a  = RA[(size_t)m * RA_N + 64 + myh];
    const float xb = a + dt_bias[myh];
    const float dt = (xb > 20.f) ? xb : log1pf(expf(xb));
    idxb[m * 8 + l] = myh;
    rwb [m * 8 + l] = e / es;
    decb[m * 8 + l] = expf(-expf(A_log[myh]) * dt);
  }
}

// ---------------------------------------------------------------- bf16 MFMA GEMM, C = A * B^T
template <bool OUT_BF16>
__global__ __launch_bounds__(256) void gemm_bt(const short* __restrict__ A,
                                               const short* __restrict__ Bm,
                                               void* __restrict__ Cout,
                                               int M, int N, int K) {
  __shared__ __align__(16) short As[128 * 32];
  __shared__ __align__(16) short Bs[128 * 32];
  const int tid = threadIdx.x;
  const int w = tid >> 6, l = tid & 63;
  const int m0 = blockIdx.y * 128, n0 = blockIdx.x * 128;
  const int wr = (w >> 1) * 64, wc = (w & 1) * 64;
  const int rsub = l >> 2, csub = (l & 3) * 8;
  const int lr = l & 15, lk = l >> 4;
  f32x4 acc[4][4] = {};

  for (int k0 = 0; k0 < K; k0 += 32) {
#pragma unroll
    for (int j = 0; j < 2; ++j) {
      const int ra = w * 32 + j * 16;
      gld_lds16(A  + (size_t)(m0 + ra + rsub) * K + k0 + csub, As + ra * 32);
      gld_lds16(Bm + (size_t)(n0 + ra + rsub) * K + k0 + csub, Bs + ra * 32);
    }
    __syncthreads();
    bf16x8 af[4], bfr[4];
#pragma unroll
    for (int i = 0; i < 4; ++i) af[i]  = *(const bf16x8*)(As + (wr + i * 16 + lr) * 32 + lk * 8);
#pragma unroll
    for (int j = 0; j < 4; ++j) bfr[j] = *(const bf16x8*)(Bs + (wc + j * 16 + lr) * 32 + lk * 8);
#pragma unroll
    for (int i = 0; i < 4; ++i)
#pragma unroll
      for (int j = 0; j < 4; ++j)
        acc[i][j] = __builtin_amdgcn_mfma_f32_16x16x32_bf16(af[i], bfr[j], acc[i][j], 0, 0, 0);
    __syncthreads();
  }
#pragma unroll
  for (int i = 0; i < 4; ++i)
#pragma unroll
    for (int j = 0; j < 4; ++j) {
      const size_t row0 = (size_t)m0 + wr + i * 16 + lk * 4;
      const size_t col  = (size_t)n0 + wc + j * 16 + lr;
#pragma unroll
      for (int r = 0; r < 4; ++r) {
        if constexpr (OUT_BF16)
          ((__hip_bfloat16*)Cout)[(row0 + r) * N + col] = __float2bfloat16(acc[i][j][r]);
        else
          ((float*)Cout)[(row0 + r) * N + col] = acc[i][j][r];
      }
    }
}

// ---------------------------------------------------------------- gather selected heads -> records
// rec[(b*K+s)*T + t][128]: k[0..32) q[32..64) v[64..96) d[96] wt[97]
__global__ __launch_bounds__(256) void gather_records(const __hip_bfloat16* __restrict__ qkv,
                                                      const int* __restrict__ idxb,
                                                      const float* __restrict__ rwb,
                                                      const float* __restrict__ decb,
                                                      float* __restrict__ rec) {
  const int w = threadIdx.x >> 6, l = threadIdx.x & 63;
  const long rid = (long)blockIdx.x * 4 + w;
  const int t  = (int)(rid & (T_ - 1));
  const int bs = (int)(rid >> 11);
  const int b = bs >> 3, s = bs & 7;
  const long m = (long)b * T_ + t;
  const int h = idxb[m * 8 + s];
  float* r = rec + rid * 128;
  const int half = l >> 5, li = l & 31;

  const long base = m * QKV_N + (long)h * 32 + li + (half ? 2048 : 0);
  const float xr = __bfloat162float(qkv[base]);
  const float sx = xr / (1.f + expf(-xr));
  float ss = sx * sx;
  ss += __shfl_xor(ss, 1);  ss += __shfl_xor(ss, 2);  ss += __shfl_xor(ss, 4);
  ss += __shfl_xor(ss, 8);  ss += __shfl_xor(ss, 16);
  const float outv = sx * rsqrtf(ss + 1e-6f);
  r[half ? li : (32 + li)] = outv;

  if (half == 0) {
    const float xv = __bfloat162float(qkv[m * QKV_N + 4096 + (long)h * 32 + li]);
    r[64 + li] = xv / (1.f + expf(-xv));
  }
  if (l == 0) { r[96] = decb[m * 8 + s]; r[97] = rwb[m * 8 + s]; }
}

// ---------------------------------------------------------------- chunked scan: pass 1
// Block = (bs, chunk). Stage 64x128 floats to LDS, local scan from S=0.
// Emits ylocal (unweighted), Sloc (end state), cumd (per-step cum decay), Pc.
__global__ __launch_bounds__(256) void scan_pass1(const float* __restrict__ rec,
                                                  float* __restrict__ ylocal,
                                                  float* __restrict__ Sloc,
                                                  float* __restrict__ Pc,
                                                  float* __restrict__ cumd) {
  __shared__ __align__(16) float R[CL_ * 128];   // 32 KB
  const int blk = blockIdx.x;
  const int bs = blk >> 5, c = blk & (NC_ - 1);
  const int t0 = c * CL_;
  const float* g = rec + ((size_t)bs * T_ + t0) * 128;
  for (int i = threadIdx.x; i < CL_ * 32; i += 256)
    *(float4*)(R + (size_t)i * 4) = *(const float4*)(g + (size_t)i * 4);
  __syncthreads();

  const int w = threadIdx.x >> 6, l = threadIdx.x & 63;
  const int v = w * 8 + (l & 7);
  const int n0 = (l >> 3) * 4;
  float s0 = 0.f, s1 = 0.f, s2 = 0.f, s3 = 0.f;
  float cum = 1.f;
  float* yl = ylocal + ((size_t)bs * T_ + t0) * 32 + v;
  float* cd = cumd + (size_t)bs * T_ + t0;

#pragma unroll 4
  for (int t = 0; t < CL_; ++t) {
    const float* r = R + t * 128;
    const float4 k4 = *(const float4*)(r + n0);
    const float4 q4 = *(const float4*)(r + 32 + n0);
    const float vv = r[64 + v];
    const float d  = r[96];
    cum *= d;
    s0 = fmaf(d, s0, k4.x * vv);
    s1 = fmaf(d, s1, k4.y * vv);
    s2 = fmaf(d, s2, k4.z * vv);
    s3 = fmaf(d, s3, k4.w * vv);
    float p = fmaf(q4.x, s0, fmaf(q4.y, s1, fmaf(q4.z, s2, q4.w * s3)));
    p += __shfl_xor(p, 8); p += __shfl_xor(p, 16); p += __shfl_xor(p, 32);
    if (l < 8) yl[(size_t)t * 32] = p;
    if (threadIdx.x == 0) cd[t] = cum;
  }
  float* sl = Sloc + (((size_t)bs * NC_ + c) * 32 + n0) * 32 + v;
  sl[0] = s0; sl[32] = s1; sl[64] = s2; sl[96] = s3;
  if (threadIdx.x == 0) Pc[bs * NC_ + c] = cum;
}

// ---------------------------------------------------------------- chunked scan: pass 2
// Block per slot. Stage all chunk S_locals (128 KB) to LDS, 32-step carry.
__global__ __launch_bounds__(256) void scan_pass2(const float* __restrict__ Sloc,
                                                  const float* __restrict__ Pc,
                                                  const float* __restrict__ S0,
                                                  float* __restrict__ Sin,
                                                  float* __restrict__ Sfin) {
  __shared__ __align__(16) float L[NC_ * 1024];  // 128 KB
  __shared__ float Ps[NC_];
  const int bs = blockIdx.x;
  const float* gl = Sloc + (size_t)bs * NC_ * 1024;
  for (int i = threadIdx.x; i < NC_ * 256; i += 256)
    *(float4*)(L + (size_t)i * 4) = *(const float4*)(gl + (size_t)i * 4);
  if (threadIdx.x < NC_) Ps[threadIdx.x] = Pc[bs * NC_ + threadIdx.x];
  __syncthreads();

  const int e0 = threadIdx.x * 4;
  float4 S = *(const float4*)(S0 + (size_t)bs * 1024 + e0);
  float* sin_b = Sin + (size_t)bs * NC_ * 1024;
#pragma unroll 4
  for (int c = 0; c < NC_; ++c) {
    *(float4*)(sin_b + (size_t)c * 1024 + e0) = S;
    const float4 sl = *(const float4*)(L + c * 1024 + e0);
    const float pc = Ps[c];
    S.x = fmaf(pc, S.x, sl.x);
    S.y = fmaf(pc, S.y, sl.y);
    S.z = fmaf(pc, S.z, sl.z);
    S.w = fmaf(pc, S.w, sl.w);
  }
  *(float4*)(Sfin + (size_t)bs * 1024 + e0) = S;
}

// ---------------------------------------------------------------- chunked scan: pass 3
// y_t = w_t * (y_local_t + c_t * q_t^T S_in[chunk]); write bf16 Y rows.
__global__ __launch_bounds__(256) void scan_pass3(const float* __restrict__ rec,
                                                  const float* __restrict__ ylocal,
                                                  const float* __restrict__ Sin,
                                                  const float* __restrict__ cumd,
                                                  __hip_bfloat16* __restrict__ Y) {
  __shared__ __align__(16) float Ss[1024];
  const int blk = blockIdx.x;
  const int bs = blk >> 5, c = blk & (NC_ - 1);
  const int b = bs >> 3, s = bs & 7;
  const int t0 = c * CL_;
  {
    const float* gs = Sin + ((size_t)bs * NC_ + c) * 1024;
    const int i = threadIdx.x;
    *(float4*)(Ss + (size_t)i * 4) = *(const float4*)(gs + (size_t)i * 4);
  }
  __syncthreads();

  const int w = threadIdx.x >> 6, l = threadIdx.x & 63;
  const int v = l & 31;
#pragma unroll
  for (int i = 0; i < 16; i += 2) {
    const int t = t0 + w * 16 + i + (l >> 5);
    const float* r = rec + ((size_t)bs * T_ + t) * 128;
    float p = 0.f;
#pragma unroll
    for (int nq = 0; nq < 8; ++nq) {
      const float4 q4 = *(const float4*)(r + 32 + nq * 4);
      p = fmaf(q4.x, Ss[(nq * 4 + 0) * 32 + v], p);
      p = fmaf(q4.y, Ss[(nq * 4 + 1) * 32 + v], p);
      p = fmaf(q4.z, Ss[(nq * 4 + 2) * 32 + v], p);
      p = fmaf(q4.w, Ss[(nq * 4 + 3) * 32 + v], p);
    }
    const float wt   = r[97];
    const float cdv  = cumd[(size_t)bs * T_ + t];
    const float yloc = ylocal[((size_t)bs * T_ + t) * 32 + v];
    const long m = (long)b * T_ + t;
    Y[(size_t)m * 256 + s * 32 + v] = __float2bfloat16(wt * (yloc + cdv * p));
  }
}

// ---------------------------------------------------------------- launch
extern "C" void kernel_launch(void* const* d_in, const int* in_sizes, int n_in,
                              void* d_out, int out_size, void* d_ws, size_t ws_size,
                              hipStream_t stream) {
  const float* x       = (const float*)d_in[0];
  const float* Wr      = (const float*)d_in[1];
  const float* Wq      = (const float*)d_in[2];
  const float* Wk      = (const float*)d_in[3];
  const float* Wv      = (const float*)d_in[4];
  const float* Wa      = (const float*)d_in[5];
  const float* A_log   = (const float*)d_in[6];
  const float* dt_bias = (const float*)d_in[7];
  const float* Wo      = (const float*)d_in[8];
  const float* S0      = (const float*)d_in[9];
  float* out = (float*)d_out;

  char* p = (char*)d_ws;
  auto alloc = [&](size_t bytes) -> void* {
    void* r = (void*)p; p += (bytes + 255) & ~(size_t)255; return r;
  };
  __hip_bfloat16* x_bf = (__hip_bfloat16*)alloc((size_t)NTOK * DIM_ * 2);
  __hip_bfloat16* Wqkv = (__hip_bfloat16*)alloc((size_t)QKV_N * DIM_ * 2);
  __hip_bfloat16* qkv  = (__hip_bfloat16*)alloc((size_t)NTOK * QKV_N * 2);
  float* WT   = (float*)alloc((size_t)DIM_ * RA_N * 4);
  float* RA   = (float*)alloc((size_t)NTOK * RA_N * 4);
  int*   idxb = (int*)  alloc((size_t)NTOK * K_ * 4);
  float* rwb  = (float*)alloc((size_t)NTOK * K_ * 4);
  float* decb = (float*)alloc((size_t)NTOK * K_ * 4);
  float* recb = (float*)alloc((size_t)NSLOT * T_ * 128 * 4);
  __hip_bfloat16* Yb = (__hip_bfloat16*)alloc((size_t)NTOK * 256 * 2);
  __hip_bfloat16* B2 = (__hip_bfloat16*)alloc((size_t)DIM_ * 256 * 2);
  float* ylocal = (float*)alloc((size_t)NSLOT * T_ * 32 * 4);
  float* Slocb  = (float*)alloc((size_t)NSLOT * NC_ * 1024 * 4);
  float* Pcb    = (float*)alloc((size_t)NSLOT * NC_ * 4);
  float* Sinb   = (float*)alloc((size_t)NSLOT * NC_ * 1024 * 4);
  float* cumdb  = (float*)alloc((size_t)NSLOT * T_ * 4);

  cast_bf16<<<NTOK * DIM_ / 4 / 256, 256, 0, stream>>>(x, x_bf, NTOK * DIM_ / 4);
  cast_bf16<<<2048, 256, 0, stream>>>(Wq, Wqkv,               2048 * 1024 / 4);
  cast_bf16<<<2048, 256, 0, stream>>>(Wk, Wqkv + 2048 * 1024, 2048 * 1024 / 4);
  cast_bf16<<<2048, 256, 0, stream>>>(Wv, Wqkv + 4096 * 1024, 2048 * 1024 / 4);
  build_b2<<<DIM_ * 256 / 256, 256, 0, stream>>>(Wo, B2);
  build_wt<<<DIM_ * RA_N / 256, 256, 0, stream>>>(Wr, Wa, WT);

  router_gemm<<<NTOK / 32, 256, 0, stream>>>(x, WT, RA);
  router_topk<<<NTOK / 4, 256, 0, stream>>>(RA, A_log, dt_bias, idxb, rwb, decb);

  gemm_bt<true><<<dim3(QKV_N / 128, NTOK / 128), 256, 0, stream>>>(
      (const short*)x_bf, (const short*)Wqkv, qkv, NTOK, QKV_N, DIM_);

  gather_records<<<NSLOT * T_ / 4, 256, 0, stream>>>(qkv, idxb, rwb, decb, recb);

  scan_pass1<<<NSLOT * NC_, 256, 0, stream>>>(recb, ylocal, Slocb, Pcb, cumdb);
  scan_pass2<<<NSLOT, 256, 0, stream>>>(Slocb, Pcb, S0, Sinb, out + (size_t)NTOK * DIM_);
  scan_pass3<<<NSLOT * NC_, 256, 0, stream>>>(recb, ylocal, Sinb, cumdb, Yb);

  gemm_bt<false><<<dim3(DIM_ / 128, NTOK / 128), 256, 0, stream>>>(
      (const short*)Yb, (const short*)B2, out, NTOK, DIM_, 256);
}